// Round 1
// baseline (188.087 us; speedup 1.0000x reference)
//
#include <hip/hip_runtime.h>
#include <math.h>

#define Bx 2
#define Sx 2048
#define Dx 1024
#define Hx 16
#define HDx 64
#define Mx (Bx*Sx)   // 4096

typedef __bf16 bf16x8 __attribute__((ext_vector_type(8)));
typedef __bf16 bf16x4 __attribute__((ext_vector_type(4)));
typedef float  f32x4  __attribute__((ext_vector_type(4)));

// 0.125 (1/sqrt(64)) * log2(e): softmax in exp2 domain; folded into Q in GEMM1
#define SCL 0.18033688011112042f

__device__ __forceinline__ void gload_lds16(const __bf16* g, __bf16* l) {
  __builtin_amdgcn_global_load_lds(
      (const __attribute__((address_space(1))) unsigned int*)g,
      (__attribute__((address_space(3))) unsigned int*)l, 16, 0, 0);
}

// ---------------- fp32 -> bf16 conversion / weight concat ----------------
__device__ __forceinline__ void cvt8(const float* s, __bf16* d) {
  float4 a = *(const float4*)s;
  float4 b = *(const float4*)(s + 4);
  bf16x8 o;
  o[0] = (__bf16)a.x; o[1] = (__bf16)a.y; o[2] = (__bf16)a.z; o[3] = (__bf16)a.w;
  o[4] = (__bf16)b.x; o[5] = (__bf16)b.y; o[6] = (__bf16)b.z; o[7] = (__bf16)b.w;
  *(bf16x8*)d = o;
}

__global__ __launch_bounds__(256) void cvt_kernel(
    const float* __restrict__ x, const float* __restrict__ Wq,
    const float* __restrict__ Wk, const float* __restrict__ Wv,
    const float* __restrict__ Wo, const float* __restrict__ bq,
    const float* __restrict__ bk, const float* __restrict__ bv,
    __bf16* __restrict__ xb, __bf16* __restrict__ wqkv,
    __bf16* __restrict__ wob, float* __restrict__ bqkv)
{
  const int bid = blockIdx.x;
  const int t = threadIdx.x;
  const size_t MEG = 1024u * 1024u;
  if (bid < 2048) {
    size_t e = (size_t)bid * 2048 + t * 8;
    cvt8(x + e, xb + e);
  } else if (bid < 3584) {
    size_t e = (size_t)(bid - 2048) * 2048 + t * 8;
    const float* src = (e < MEG) ? (Wq + e) : (e < 2 * MEG) ? (Wk + (e - MEG)) : (Wv + (e - 2 * MEG));
    cvt8(src, wqkv + e);
  } else if (bid < 4096) {
    size_t e = (size_t)(bid - 3584) * 2048 + t * 8;
    cvt8(Wo + e, wob + e);
  } else {
    for (int i = t; i < 3072; i += 256)
      bqkv[i] = (i < 1024) ? bq[i] : (i < 2048) ? bk[i - 1024] : bv[i - 2048];
  }
}

// ---------------- bf16 MFMA GEMM, stage-ahead pipelined (unchanged) ----------
template<int TM, int TN, int MODE>
__global__ __launch_bounds__(256) void gemm_k(
    const __bf16* __restrict__ A, const __bf16* __restrict__ W,
    const float* __restrict__ bias, float* __restrict__ Cf,
    __bf16* __restrict__ Cb, __bf16* __restrict__ vT,
    int M, int N, int K, int ldc)
{
  __shared__ __align__(16) char smem[2 * (TM + TN) * 64 * 2];
  __bf16* AsB = (__bf16*)smem;

  constexpr int MS = TM / 32;
  constexpr int NS = TN / 32;
  const int tid = threadIdx.x;
  const int lane = tid & 63, wave = tid >> 6;
  const int l16 = lane & 15, quad = lane >> 4;
  const int wm = (wave >> 1) * (TM / 2);
  const int wn = (wave & 1) * (TN / 2);
  const int swz = l16 & 7;

  // 64-block supertile swizzle (8 m-tiles x 8 n-tiles)
  const int lid = blockIdx.y * gridDim.x + blockIdx.x;
  const int g8 = lid >> 6;
  const int r64 = lid & 63;
  const int gpm = (int)gridDim.y >> 3;
  const int gm = g8 % gpm;
  const int gn = g8 / gpm;
  const int m0 = (gm * 8 + (r64 & 7)) * TM;
  const int n0 = (gn * 8 + (r64 >> 3)) * TN;

  const f32x4 zero = {0.f, 0.f, 0.f, 0.f};
  f32x4 acc[MS][NS];
#pragma unroll
  for (int i = 0; i < MS; ++i)
#pragma unroll
    for (int j = 0; j < NS; ++j) acc[i][j] = zero;

  const int srow = tid >> 3;
  const int scs = (tid & 7) ^ (srow & 7);
  const __bf16* Ag = A + (size_t)(m0 + srow) * K + scs * 8;
  const __bf16* Wg = W + (size_t)(n0 + srow) * K + scs * 8;

#define G_STAGE(k0_, b_)                                                        \
  { __bf16* As_ = AsB + (b_) * (TM + TN) * 64;                                  \
    __bf16* Bs_ = As_ + TM * 64;                                                \
    _Pragma("unroll")                                                           \
    for (int i = 0; i < TM / 32; ++i)                                           \
      gload_lds16(Ag + (size_t)(i * 32) * K + (k0_), &As_[(i * 256 + tid) * 8]);\
    _Pragma("unroll")                                                           \
    for (int i = 0; i < TN / 32; ++i)                                           \
      gload_lds16(Wg + (size_t)(i * 32) * K + (k0_), &Bs_[(i * 256 + tid) * 8]); }

  const int NT = K >> 6;
  G_STAGE(0, 0)
  __syncthreads();

  for (int t = 0; t < NT; ++t) {
    if (t + 1 < NT) G_STAGE((t + 1) << 6, (t + 1) & 1)
    const __bf16* As_ = AsB + (t & 1) * (TM + TN) * 64;
    const __bf16* Bs_ = As_ + TM * 64;
#pragma unroll
    for (int hk = 0; hk < 2; ++hk) {
      const int ph = ((hk * 4 + quad) ^ swz) * 8;
      bf16x8 af[MS], bfr[NS];
#pragma unroll
      for (int i = 0; i < MS; ++i)
        af[i] = *(const bf16x8*)&As_[(wm + i * 16 + l16) * 64 + ph];
#pragma unroll
      for (int j = 0; j < NS; ++j)
        bfr[j] = *(const bf16x8*)&Bs_[(wn + j * 16 + l16) * 64 + ph];
#pragma unroll
      for (int i = 0; i < MS; ++i)
#pragma unroll
        for (int j = 0; j < NS; ++j)
          acc[i][j] = __builtin_amdgcn_mfma_f32_16x16x32_bf16(af[i], bfr[j], acc[i][j], 0, 0, 0);
    }
    __syncthreads();   // (a) everyone done with buf t; (b) stage(t+1) drained
  }

  // ---- epilogue: stage C tile in LDS (aliases staging bufs), 16B stores ----
  if (MODE == 0) {
    float* Cs = (float*)smem;          // [TM][TN+4]
    constexpr int cst = TN + 4;
#pragma unroll
    for (int j = 0; j < NS; ++j) {
      const int c = wn + j * 16 + l16;
      const float bv_ = bias[n0 + c];
#pragma unroll
      for (int i = 0; i < MS; ++i) {
        const int r0 = wm + i * 16 + quad * 4;
#pragma unroll
        for (int g = 0; g < 4; ++g)
          Cs[(r0 + g) * cst + c] = acc[i][j][g] + bv_;
      }
    }
    __syncthreads();
    constexpr int passes = TM * TN / (256 * 4);
#pragma unroll
    for (int p = 0; p < passes; ++p) {
      const int slot = p * 256 + tid;
      const int row = slot / (TN / 4);
      const int col4 = (slot % (TN / 4)) * 4;
      f32x4 v = *(const f32x4*)&Cs[row * cst + col4];
      *(f32x4*)&Cf[(size_t)(m0 + row) * ldc + n0 + col4] = v;
    }
  } else {
    __bf16* Cs = (__bf16*)smem;
    constexpr int cst = TN + 8;
    const bool vtile = (n0 >= 2048);
    if (!vtile) {
#pragma unroll
      for (int j = 0; j < NS; ++j) {
        const int c = wn + j * 16 + l16;
        const float bv_ = bias[n0 + c];
        const float sc = ((n0 + c) < 1024) ? SCL : 1.0f;
#pragma unroll
        for (int i = 0; i < MS; ++i) {
          const int r0 = wm + i * 16 + quad * 4;
#pragma unroll
          for (int g = 0; g < 4; ++g)
            Cs[(r0 + g) * cst + c] = (__bf16)((acc[i][j][g] + bv_) * sc);
        }
      }
      __syncthreads();
      constexpr int passes = TM * TN / (256 * 8);
#pragma unroll
      for (int p = 0; p < passes; ++p) {
        const int slot = p * 256 + tid;
        const int row = slot / (TN / 8);
        const int col8 = (slot % (TN / 8)) * 8;
        bf16x8 v = *(const bf16x8*)&Cs[row * cst + col8];
        *(bf16x8*)&Cb[(size_t)(m0 + row) * 3072 + n0 + col8] = v;
      }
    } else {
      constexpr int cstT = TM + 8;
#pragma unroll
      for (int j = 0; j < NS; ++j) {
        const int c = wn + j * 16 + l16;
        const float bv_ = bias[n0 + c];
#pragma unroll
        for (int i = 0; i < MS; ++i) {
          const int r0 = wm + i * 16 + quad * 4;
#pragma unroll
          for (int g = 0; g < 4; ++g)
            Cs[c * cstT + r0 + g] = (__bf16)(acc[i][j][g] + bv_);
        }
      }
      __syncthreads();
      const int bb = m0 >> 11, ml = m0 & 2047;
      constexpr int passes = TM * TN / (256 * 8);
#pragma unroll
      for (int p = 0; p < passes; ++p) {
        const int slot = p * 256 + tid;
        const int dd = slot / (TM / 8);
        const int ss8 = (slot % (TM / 8)) * 8;
        bf16x8 v = *(const bf16x8*)&Cs[dd * cstT + ss8];
        const int c2 = n0 - 2048 + dd;
        const int hh = c2 >> 6, ddd = c2 & 63;
        *(bf16x8*)&vT[((size_t)(bb * 16 + hh) * 64 + ddd) * 2048 + ml + ss8] = v;
      }
    }
  }
}

// ---------------- MFMA flash attention, S^T formulation ----------------
// r11: QBLK=128 (4 waves x 32 q-rows, 2 q-subtiles/wave). Each K/V fragment
// read from LDS now feeds TWO MFMAs (was one) -> LDS read traffic per FLOP
// x0.55, barriers & staging per FLOP x0.5, 2x per-wave MFMA ILP. LDS = 56KB
// (Q/P 16K + K 2x8K + V 3x8K) -> 2 blocks/CU, grid 512 = all co-resident.
// Anti-correlated block pairing: block i (qt=15-g) and i+256 (qt=g) sum to
// constant 34 key-tiles so the usual i%256 CU round-robin balances perfectly;
// phase 0 is all-heavy as a hedge.
__global__ __launch_bounds__(256, 2) void attn_mfma(
    const __bf16* __restrict__ qkv, const __bf16* __restrict__ vT,
    __bf16* __restrict__ zb)
{
  __shared__ __bf16 Qs[128 * 64];     // Q; later per-wave P slices (2 subtiles)
  __shared__ __bf16 Ks[2][64 * 64];
  __shared__ __bf16 Vs[3][64 * 64];   // [d][k] (from vT)

  const int tid = threadIdx.x;
  const int lane = tid & 63, wave = tid >> 6;
  const int l16 = lane & 15, quad = lane >> 4;
  const int bx = blockIdx.x;
  const int jj = bx & 255;
  const int bh = jj & 31;
  const int gg = jj >> 5;                 // 0..7
  const int qt = (bx >> 8) ? gg : (15 - gg);   // phase0: 15..8, phase1: 0..7
  const int q0 = qt * 128;
  const int h = bh & 15, b = bh >> 4;

  const __bf16* qg = qkv + (size_t)b * 2048 * 3072 + h * 64;
  const __bf16* kg = qg + 1024;
  const __bf16* vg = vT + (size_t)bh * 64 * 2048;

#define STAGE_KV(kt_, kbuf, vbuf)                                               \
  { const int kn = (kt_) * 64;                                                  \
    _Pragma("unroll")                                                           \
    for (int i = 0; i < 2; ++i) {                                               \
      int slot = i * 256 + tid;                                                 \
      int row = slot >> 3, ph2 = slot & 7;                                      \
      int cs = ph2 ^ (row & 7);                                                 \
      gload_lds16(kg + (size_t)(kn + row) * 3072 + cs * 8, &Ks[kbuf][slot * 8]);\
      gload_lds16(vg + (size_t)row * 2048 + kn + cs * 8, &Vs[vbuf][slot * 8]);  \
    } }

  // prologue: Q (128 rows) + K/V tile 0
#pragma unroll
  for (int i = 0; i < 4; ++i) {
    int slot = i * 256 + tid;
    int row = slot >> 3, ph2 = slot & 7;
    int cs = ph2 ^ (row & 7);
    gload_lds16(qg + (size_t)(q0 + row) * 3072 + cs * 8, &Qs[slot * 8]);
  }
  STAGE_KV(0, 0, 0)
  __syncthreads();

  const int swz = l16 & 7;
  const int sw0 = (quad ^ swz) * 8;
  const int sw1 = ((quad + 4) ^ swz) * 8;

  // Q fragments for both q-subtiles (loop-invariant), B operand of S^T = K.Q^T
  bf16x8 qf0[2], qf1[2];
#pragma unroll
  for (int n = 0; n < 2; ++n) {
    const int r = wave * 32 + n * 16 + l16;
    qf0[n] = *(const bf16x8*)&Qs[r * 64 + sw0];
    qf1[n] = *(const bf16x8*)&Qs[r * 64 + sw1];
  }
  __bf16* P = &Qs[wave * 32 * 64];    // this wave's own 32x64 slice (2x 16x64)

  // ones B-frag: B[n=0][k]=1 -> col 0 of Ol = row-sum of P (the l vector)
  bf16x8 onesf;
  {
    __bf16 ov = (l16 == 0) ? (__bf16)1.0f : (__bf16)0.0f;
#pragma unroll
    for (int i = 0; i < 8; ++i) onesf[i] = ov;
  }

  const f32x4 zero = {0.f, 0.f, 0.f, 0.f};
  f32x4 O[4][2], Ol[2];
#pragma unroll
  for (int j = 0; j < 4; ++j) { O[j][0] = zero; O[j][1] = zero; }
  Ol[0] = zero; Ol[1] = zero;
  f32x4 s_cur[4][2], s_next[4][2];   // S^T: lane holds [key=m*16+quad*4+g][q=l16]

#define S_TILE(sdst, kb)                                                        \
  { _Pragma("unroll")                                                           \
    for (int m = 0; m < 4; ++m) {                                               \
      bf16x8 kf0 = *(const bf16x8*)&Ks[kb][(m * 16 + l16) * 64 + sw0];          \
      bf16x8 kf1 = *(const bf16x8*)&Ks[kb][(m * 16 + l16) * 64 + sw1];          \
      _Pragma("unroll")                                                         \
      for (int n = 0; n < 2; ++n) {                                             \
        sdst[m][n] = zero;                                                      \
        sdst[m][n] = __builtin_amdgcn_mfma_f32_16x16x32_bf16(kf0, qf0[n], sdst[m][n],0,0,0); \
        sdst[m][n] = __builtin_amdgcn_mfma_f32_16x16x32_bf16(kf1, qf1[n], sdst[m][n],0,0,0); \
      } } }

  // mask if KOFF + key_local > q_local  (key_local = m*16+quad*4+g,
  // q_local = wave*32 + n*16 + l16); KOFF=0 for tile NT-2, 64 for tile NT-1
#define EXP_P(s, DIAG, KOFF)                                                    \
  { _Pragma("unroll")                                                           \
    for (int m = 0; m < 4; ++m) {                                               \
      const int kl = (KOFF) + m * 16 + quad * 4;                                \
      _Pragma("unroll")                                                         \
      for (int n = 0; n < 2; ++n) {                                             \
        const int ql = wave * 32 + n * 16 + l16;                                \
        bf16x4 st;                                                              \
        _Pragma("unroll")                                                       \
        for (int g = 0; g < 4; ++g) {                                           \
          float p = __builtin_exp2f(s[m][n][g]);                                \
          if (DIAG && (kl + g) > ql) p = 0.f;                                   \
          st[g] = (__bf16)p;                                                    \
        }                                                                       \
        *(bf16x4*)&P[n * 1024 + l16 * 64 + (((2 * m + (quad >> 1)) ^ swz) * 8) + (quad & 1) * 4] = st; \
      } } }

#define PV_TILE(vb)                                                             \
  { bf16x8 pf0[2], pf1[2];                                                      \
    _Pragma("unroll")                                                           \
    for (int n = 0; n < 2; ++n) {                                               \
      pf0[n] = *(const bf16x8*)&P[n * 1024 + l16 * 64 + sw0];                   \
      pf1[n] = *(const bf16x8*)&P[n * 1024 + l16 * 64 + sw1];                   \
    }                                                                           \
    _Pragma("unroll")                                                           \
    for (int j = 0; j < 4; ++j) {                                               \
      bf16x8 vf0 = *(const bf16x8*)&Vs[vb][(j * 16 + l16) * 64 + sw0];          \
      bf16x8 vf1 = *(const bf16x8*)&Vs[vb][(j * 16 + l16) * 64 + sw1];          \
      _Pragma("unroll")                                                         \
      for (int n = 0; n < 2; ++n) {                                             \
        O[j][n] = __builtin_amdgcn_mfma_f32_16x16x32_bf16(pf0[n], vf0, O[j][n], 0, 0, 0); \
        O[j][n] = __builtin_amdgcn_mfma_f32_16x16x32_bf16(pf1[n], vf1, O[j][n], 0, 0, 0); \
      }                                                                         \
    }                                                                           \
    _Pragma("unroll")                                                           \
    for (int n = 0; n < 2; ++n) {                                               \
      Ol[n] = __builtin_amdgcn_mfma_f32_16x16x32_bf16(pf0[n], onesf, Ol[n], 0, 0, 0); \
      Ol[n] = __builtin_amdgcn_mfma_f32_16x16x32_bf16(pf1[n], onesf, Ol[n], 0, 0, 0); \
    } }

  const int NT = 2 * qt + 2;          // 64-key tiles for this 128-q block

  // pipeline prologue: stage tile 1, compute S^T(0)
  STAGE_KV(1, 1, 1)
  S_TILE(s_cur, 0)
  __syncthreads();   // drains stage(1)

  for (int t = 0; t < NT - 1; ++t) {
    if (t < NT - 2) { EXP_P(s_cur, false, 0) }   // VALU of tile t ...
    else            { EXP_P(s_cur, true, 0) }    // tile NT-2 clips waves 0/1
    if (t < NT - 2 || wave >= 2) S_TILE(s_next, (t + 1) & 1)  // ... overlaps MFMA t+1
    PV_TILE(t % 3)
    if (t + 2 < NT) STAGE_KV(t + 2, t & 1, (t + 2) % 3)
    __syncthreads();
#pragma unroll
    for (int m = 0; m < 4; ++m) { s_cur[m][0] = s_next[m][0]; s_cur[m][1] = s_next[m][1]; }
  }
  // final tile: keys [q0+64, q0+128) -> only waves 2,3 (rows >= q0+64) contribute
  if (wave >= 2) {
    EXP_P(s_cur, true, 64)
    PV_TILE((NT - 1) % 3)
  }

  // epilogue: l lives in col 0 of Ol (lanes l16==0); broadcast within quad
#pragma unroll
  for (int n = 0; n < 2; ++n) {
    const int rq = q0 + wave * 32 + n * 16 + quad * 4;
#pragma unroll
    for (int g = 0; g < 4; ++g) {
      const float lv = __shfl(Ol[n][g], quad * 16);
      const float inv = 1.0f / lv;
      const size_t rb = (size_t)(b * 2048 + rq + g) * 1024 + h * 64 + l16;
#pragma unroll
      for (int j = 0; j < 4; ++j)
        zb[rb + j * 16] = (__bf16)(O[j][n][g] * inv);
    }
  }
}

// ---------------- launch ----------------
extern "C" void kernel_launch(void* const* d_in, const int* in_sizes, int n_in,
                              void* d_out, int out_size, void* d_ws, size_t ws_size,
                              hipStream_t stream) {
  (void)in_sizes; (void)n_in; (void)out_size; (void)ws_size;
  const float* x  = (const float*)d_in[0];
  const float* Wq = (const float*)d_in[1];
  const float* bq = (const float*)d_in[2];
  const float* Wk = (const float*)d_in[3];
  const float* bk = (const float*)d_in[4];
  const float* Wv = (const float*)d_in[5];
  const float* bv = (const float*)d_in[6];
  const float* Wo = (const float*)d_in[7];
  const float* bo = (const float*)d_in[8];

  char* ws = (char*)d_ws;
  __bf16* xb   = (__bf16*)(ws);                        // 8 MB
  __bf16* wqkv = (__bf16*)(ws + (8ull  << 20));        // 6 MB
  __bf16* wob  = (__bf16*)(ws + (14ull << 20));        // 2 MB
  float*  bqkv = (float*) (ws + (16ull << 20));        // 12 KB
  __bf16* qkv  = (__bf16*)(ws + (17ull << 20));        // 24 MB
  __bf16* vT   = (__bf16*)(ws + (41ull << 20));        // 8 MB  [bh][64][2048]
  __bf16* zb   = (__bf16*)(ws + (49ull << 20));        // 8 MB  (total 57 MB)

  cvt_kernel<<<4097, 256, 0, stream>>>(x, Wq, Wk, Wv, Wo, bq, bk, bv,
                                       xb, wqkv, wob, bqkv);
  gemm_k<128, 128, 1><<<dim3(24, 32), 256, 0, stream>>>(
      xb, wqkv, bqkv, nullptr, qkv, vT, Mx, 3072, 1024, 0);
  attn_mfma<<<512, 256, 0, stream>>>(qkv, vT, zb);
  gemm_k<128, 64, 0><<<dim3(16, 32), 256, 0, stream>>>(
      zb, wob, bo, (float*)d_out, nullptr, nullptr, Mx, 1024, 1024, 1024);
}

// Round 2
// 183.204 us; speedup vs baseline: 1.0267x; 1.0267x over previous
//
#include <hip/hip_runtime.h>
#include <math.h>

#define Bx 2
#define Sx 2048
#define Dx 1024
#define Hx 16
#define HDx 64
#define Mx (Bx*Sx)   // 4096

typedef __bf16 bf16x8 __attribute__((ext_vector_type(8)));
typedef __bf16 bf16x4 __attribute__((ext_vector_type(4)));
typedef float  f32x4  __attribute__((ext_vector_type(4)));

// 0.125 (1/sqrt(64)) * log2(e): softmax in exp2 domain; folded into Q in GEMM1
#define SCL 0.18033688011112042f

__device__ __forceinline__ void gload_lds16(const __bf16* g, __bf16* l) {
  __builtin_amdgcn_global_load_lds(
      (const __attribute__((address_space(1))) unsigned int*)g,
      (__attribute__((address_space(3))) unsigned int*)l, 16, 0, 0);
}

// ---------------- fp32 -> bf16 conversion / weight concat ----------------
__device__ __forceinline__ void cvt8(const float* s, __bf16* d) {
  float4 a = *(const float4*)s;
  float4 b = *(const float4*)(s + 4);
  bf16x8 o;
  o[0] = (__bf16)a.x; o[1] = (__bf16)a.y; o[2] = (__bf16)a.z; o[3] = (__bf16)a.w;
  o[4] = (__bf16)b.x; o[5] = (__bf16)b.y; o[6] = (__bf16)b.z; o[7] = (__bf16)b.w;
  *(bf16x8*)d = o;
}

__global__ __launch_bounds__(256) void cvt_kernel(
    const float* __restrict__ x, const float* __restrict__ Wq,
    const float* __restrict__ Wk, const float* __restrict__ Wv,
    const float* __restrict__ Wo, const float* __restrict__ bq,
    const float* __restrict__ bk, const float* __restrict__ bv,
    __bf16* __restrict__ xb, __bf16* __restrict__ wqkv,
    __bf16* __restrict__ wob, float* __restrict__ bqkv)
{
  const int bid = blockIdx.x;
  const int t = threadIdx.x;
  const size_t MEG = 1024u * 1024u;
  if (bid < 2048) {
    size_t e = (size_t)bid * 2048 + t * 8;
    cvt8(x + e, xb + e);
  } else if (bid < 3584) {
    size_t e = (size_t)(bid - 2048) * 2048 + t * 8;
    const float* src = (e < MEG) ? (Wq + e) : (e < 2 * MEG) ? (Wk + (e - MEG)) : (Wv + (e - 2 * MEG));
    cvt8(src, wqkv + e);
  } else if (bid < 4096) {
    size_t e = (size_t)(bid - 3584) * 2048 + t * 8;
    cvt8(Wo + e, wob + e);
  } else {
    for (int i = t; i < 3072; i += 256)
      bqkv[i] = (i < 1024) ? bq[i] : (i < 2048) ? bk[i - 1024] : bv[i - 2048];
  }
}

// ---------------- bf16 MFMA GEMM, stage-ahead pipelined (unchanged) ----------
template<int TM, int TN, int MODE>
__global__ __launch_bounds__(256) void gemm_k(
    const __bf16* __restrict__ A, const __bf16* __restrict__ W,
    const float* __restrict__ bias, float* __restrict__ Cf,
    __bf16* __restrict__ Cb, __bf16* __restrict__ vT,
    int M, int N, int K, int ldc)
{
  __shared__ __align__(16) char smem[2 * (TM + TN) * 64 * 2];
  __bf16* AsB = (__bf16*)smem;

  constexpr int MS = TM / 32;
  constexpr int NS = TN / 32;
  const int tid = threadIdx.x;
  const int lane = tid & 63, wave = tid >> 6;
  const int l16 = lane & 15, quad = lane >> 4;
  const int wm = (wave >> 1) * (TM / 2);
  const int wn = (wave & 1) * (TN / 2);
  const int swz = l16 & 7;

  // 64-block supertile swizzle (8 m-tiles x 8 n-tiles)
  const int lid = blockIdx.y * gridDim.x + blockIdx.x;
  const int g8 = lid >> 6;
  const int r64 = lid & 63;
  const int gpm = (int)gridDim.y >> 3;
  const int gm = g8 % gpm;
  const int gn = g8 / gpm;
  const int m0 = (gm * 8 + (r64 & 7)) * TM;
  const int n0 = (gn * 8 + (r64 >> 3)) * TN;

  const f32x4 zero = {0.f, 0.f, 0.f, 0.f};
  f32x4 acc[MS][NS];
#pragma unroll
  for (int i = 0; i < MS; ++i)
#pragma unroll
    for (int j = 0; j < NS; ++j) acc[i][j] = zero;

  const int srow = tid >> 3;
  const int scs = (tid & 7) ^ (srow & 7);
  const __bf16* Ag = A + (size_t)(m0 + srow) * K + scs * 8;
  const __bf16* Wg = W + (size_t)(n0 + srow) * K + scs * 8;

#define G_STAGE(k0_, b_)                                                        \
  { __bf16* As_ = AsB + (b_) * (TM + TN) * 64;                                  \
    __bf16* Bs_ = As_ + TM * 64;                                                \
    _Pragma("unroll")                                                           \
    for (int i = 0; i < TM / 32; ++i)                                           \
      gload_lds16(Ag + (size_t)(i * 32) * K + (k0_), &As_[(i * 256 + tid) * 8]);\
    _Pragma("unroll")                                                           \
    for (int i = 0; i < TN / 32; ++i)                                           \
      gload_lds16(Wg + (size_t)(i * 32) * K + (k0_), &Bs_[(i * 256 + tid) * 8]); }

  const int NT = K >> 6;
  G_STAGE(0, 0)
  __syncthreads();

  for (int t = 0; t < NT; ++t) {
    if (t + 1 < NT) G_STAGE((t + 1) << 6, (t + 1) & 1)
    const __bf16* As_ = AsB + (t & 1) * (TM + TN) * 64;
    const __bf16* Bs_ = As_ + TM * 64;
#pragma unroll
    for (int hk = 0; hk < 2; ++hk) {
      const int ph = ((hk * 4 + quad) ^ swz) * 8;
      bf16x8 af[MS], bfr[NS];
#pragma unroll
      for (int i = 0; i < MS; ++i)
        af[i] = *(const bf16x8*)&As_[(wm + i * 16 + l16) * 64 + ph];
#pragma unroll
      for (int j = 0; j < NS; ++j)
        bfr[j] = *(const bf16x8*)&Bs_[(wn + j * 16 + l16) * 64 + ph];
#pragma unroll
      for (int i = 0; i < MS; ++i)
#pragma unroll
        for (int j = 0; j < NS; ++j)
          acc[i][j] = __builtin_amdgcn_mfma_f32_16x16x32_bf16(af[i], bfr[j], acc[i][j], 0, 0, 0);
    }
    __syncthreads();   // (a) everyone done with buf t; (b) stage(t+1) drained
  }

  // ---- epilogue: stage C tile in LDS (aliases staging bufs), 16B stores ----
  if (MODE == 0) {
    float* Cs = (float*)smem;          // [TM][TN+4]
    constexpr int cst = TN + 4;
#pragma unroll
    for (int j = 0; j < NS; ++j) {
      const int c = wn + j * 16 + l16;
      const float bv_ = bias[n0 + c];
#pragma unroll
      for (int i = 0; i < MS; ++i) {
        const int r0 = wm + i * 16 + quad * 4;
#pragma unroll
        for (int g = 0; g < 4; ++g)
          Cs[(r0 + g) * cst + c] = acc[i][j][g] + bv_;
      }
    }
    __syncthreads();
    constexpr int passes = TM * TN / (256 * 4);
#pragma unroll
    for (int p = 0; p < passes; ++p) {
      const int slot = p * 256 + tid;
      const int row = slot / (TN / 4);
      const int col4 = (slot % (TN / 4)) * 4;
      f32x4 v = *(const f32x4*)&Cs[row * cst + col4];
      *(f32x4*)&Cf[(size_t)(m0 + row) * ldc + n0 + col4] = v;
    }
  } else {
    __bf16* Cs = (__bf16*)smem;
    constexpr int cst = TN + 8;
    const bool vtile = (n0 >= 2048);
    if (!vtile) {
#pragma unroll
      for (int j = 0; j < NS; ++j) {
        const int c = wn + j * 16 + l16;
        const float bv_ = bias[n0 + c];
        const float sc = ((n0 + c) < 1024) ? SCL : 1.0f;
#pragma unroll
        for (int i = 0; i < MS; ++i) {
          const int r0 = wm + i * 16 + quad * 4;
#pragma unroll
          for (int g = 0; g < 4; ++g)
            Cs[(r0 + g) * cst + c] = (__bf16)((acc[i][j][g] + bv_) * sc);
        }
      }
      __syncthreads();
      constexpr int passes = TM * TN / (256 * 8);
#pragma unroll
      for (int p = 0; p < passes; ++p) {
        const int slot = p * 256 + tid;
        const int row = slot / (TN / 8);
        const int col8 = (slot % (TN / 8)) * 8;
        bf16x8 v = *(const bf16x8*)&Cs[row * cst + col8];
        *(bf16x8*)&Cb[(size_t)(m0 + row) * 3072 + n0 + col8] = v;
      }
    } else {
      constexpr int cstT = TM + 8;
#pragma unroll
      for (int j = 0; j < NS; ++j) {
        const int c = wn + j * 16 + l16;
        const float bv_ = bias[n0 + c];
#pragma unroll
        for (int i = 0; i < MS; ++i) {
          const int r0 = wm + i * 16 + quad * 4;
#pragma unroll
          for (int g = 0; g < 4; ++g)
            Cs[c * cstT + r0 + g] = (__bf16)(acc[i][j][g] + bv_);
        }
      }
      __syncthreads();
      const int bb = m0 >> 11, ml = m0 & 2047;
      constexpr int passes = TM * TN / (256 * 8);
#pragma unroll
      for (int p = 0; p < passes; ++p) {
        const int slot = p * 256 + tid;
        const int dd = slot / (TM / 8);
        const int ss8 = (slot % (TM / 8)) * 8;
        bf16x8 v = *(const bf16x8*)&Cs[dd * cstT + ss8];
        const int c2 = n0 - 2048 + dd;
        const int hh = c2 >> 6, ddd = c2 & 63;
        *(bf16x8*)&vT[((size_t)(bb * 16 + hh) * 64 + ddd) * 2048 + ml + ss8] = v;
      }
    }
  }
}

// ---------------- MFMA flash attention, S^T formulation ----------------
// r12: back to the proven 64-q / 4-wave structure (r10), with:
//  - V double-buffered at stage-distance 1 (was triple @ distance 2):
//    LDS 48KB -> 40KB => 4 blocks/CU (16 waves/CU, was 12). r11 showed this
//    kernel is latency-bound: wave count beats per-wave efficiency.
//  - stages issued right after EXP_P so S_TILE+PV MFMAs cover load latency
//    before the barrier drain (r10 issued them just before the barrier).
//  - balanced qt mapping: CU slot r gets qt in {s,15-s,16+s,31-s} -> every
//    CU sums to 66 key-tiles (was 52..80 spread).
//  - s_setprio(1) around MFMA clusters (T5; 4 independent blocks/CU now).
__global__ __launch_bounds__(256, 4) void attn_mfma(
    const __bf16* __restrict__ qkv, const __bf16* __restrict__ vT,
    __bf16* __restrict__ zb)
{
  __shared__ __bf16 Qs[64 * 64];      // Q; later per-wave P slices
  __shared__ __bf16 Ks[2][64 * 64];
  __shared__ __bf16 Vs[2][64 * 64];   // [d][k] (from vT)

  const int tid = threadIdx.x;
  const int lane = tid & 63, wave = tid >> 6;
  const int l16 = lane & 15, quad = lane >> 4;
  const int bx = blockIdx.x;
  const int bh = bx & 31;
  const int s8 = (bx >> 5) & 7;
  const int p4 = bx >> 8;
  const int qt = (p4 == 0) ? s8 : (p4 == 1) ? 15 - s8 : (p4 == 2) ? 16 + s8 : 31 - s8;
  const int h = bh & 15, b = bh >> 4;
  const int q0 = qt * 64;

  const __bf16* qg = qkv + (size_t)b * 2048 * 3072 + h * 64;
  const __bf16* kg = qg + 1024;
  const __bf16* vg = vT + (size_t)bh * 64 * 2048;

#define STAGE_K(kt_, kbuf)                                                      \
  { const int kn = (kt_) * 64;                                                  \
    _Pragma("unroll")                                                           \
    for (int i = 0; i < 2; ++i) {                                               \
      int slot = i * 256 + tid;                                                 \
      int row = slot >> 3, ph2 = slot & 7;                                      \
      int cs = ph2 ^ (row & 7);                                                 \
      gload_lds16(kg + (size_t)(kn + row) * 3072 + cs * 8, &Ks[kbuf][slot * 8]);\
    } }

#define STAGE_V(kt_, vbuf)                                                      \
  { const int kn = (kt_) * 64;                                                  \
    _Pragma("unroll")                                                           \
    for (int i = 0; i < 2; ++i) {                                               \
      int slot = i * 256 + tid;                                                 \
      int row = slot >> 3, ph2 = slot & 7;                                      \
      int cs = ph2 ^ (row & 7);                                                 \
      gload_lds16(vg + (size_t)row * 2048 + kn + cs * 8, &Vs[vbuf][slot * 8]);  \
    } }

  // prologue: Q + K/V tile 0
#pragma unroll
  for (int i = 0; i < 2; ++i) {
    int slot = i * 256 + tid;
    int row = slot >> 3, ph2 = slot & 7;
    int cs = ph2 ^ (row & 7);
    gload_lds16(qg + (size_t)(q0 + row) * 3072 + cs * 8, &Qs[slot * 8]);
  }
  STAGE_K(0, 0)
  STAGE_V(0, 0)
  __syncthreads();

  const int swz = l16 & 7;
  const int sw0 = ((quad) ^ swz) * 8;
  const int sw1 = ((quad + 4) ^ swz) * 8;
  const int mrow = wave * 16 + l16;

  // Q fragments (loop-invariant), used as the B operand of S^T = K.Q^T
  bf16x8 qf0 = *(const bf16x8*)&Qs[mrow * 64 + sw0];
  bf16x8 qf1 = *(const bf16x8*)&Qs[mrow * 64 + sw1];
  __bf16* P = &Qs[wave * 16 * 64];    // this wave's own 16x64 slice

  // ones B-frag: B[n=0][k]=1 -> col 0 of Ol = row-sum of P (the l vector)
  bf16x8 onesf;
  {
    __bf16 ov = (l16 == 0) ? (__bf16)1.0f : (__bf16)0.0f;
#pragma unroll
    for (int i = 0; i < 8; ++i) onesf[i] = ov;
  }

  const f32x4 zero = {0.f, 0.f, 0.f, 0.f};
  f32x4 O[4], Ol = zero;
#pragma unroll
  for (int j = 0; j < 4; ++j) O[j] = zero;
  f32x4 s_cur[4], s_next[4];   // S^T: lane holds [key=m*16+quad*4+g][q=l16]

#define S_TILE(sdst, kb)                                                        \
  { __builtin_amdgcn_s_setprio(1);                                              \
    _Pragma("unroll")                                                           \
    for (int m = 0; m < 4; ++m) sdst[m] = zero;                                 \
    _Pragma("unroll")                                                           \
    for (int m = 0; m < 4; ++m) {                                               \
      bf16x8 kf0 = *(const bf16x8*)&Ks[kb][(m * 16 + l16) * 64 + sw0];          \
      sdst[m] = __builtin_amdgcn_mfma_f32_16x16x32_bf16(kf0, qf0, sdst[m],0,0,0);\
      bf16x8 kf1 = *(const bf16x8*)&Ks[kb][(m * 16 + l16) * 64 + sw1];          \
      sdst[m] = __builtin_amdgcn_mfma_f32_16x16x32_bf16(kf1, qf1, sdst[m],0,0,0);\
    }                                                                           \
    __builtin_amdgcn_s_setprio(0); }

#define EXP_P(s, DIAG)                                                          \
  { _Pragma("unroll")                                                           \
    for (int m = 0; m < 4; ++m) {                                               \
      const int kl = m * 16 + quad * 4;                                         \
      bf16x4 st;                                                                \
      _Pragma("unroll")                                                         \
      for (int g = 0; g < 4; ++g) {                                             \
        float p = __builtin_exp2f(s[m][g]);                                     \
        if (DIAG && (kl + g) > (wave * 16 + l16)) p = 0.f;                      \
        st[g] = (__bf16)p;                                                      \
      }                                                                         \
      *(bf16x4*)&P[l16 * 64 + (((2 * m + (quad >> 1)) ^ swz) * 8) + (quad & 1) * 4] = st; \
    } }

#define PV_TILE(vb)                                                             \
  { bf16x8 pf0 = *(const bf16x8*)&P[l16 * 64 + sw0];                            \
    bf16x8 pf1 = *(const bf16x8*)&P[l16 * 64 + sw1];                            \
    __builtin_amdgcn_s_setprio(1);                                              \
    _Pragma("unroll")                                                           \
    for (int j = 0; j < 4; ++j) {                                               \
      bf16x8 vf0 = *(const bf16x8*)&Vs[vb][(j * 16 + l16) * 64 + sw0];          \
      O[j] = __builtin_amdgcn_mfma_f32_16x16x32_bf16(pf0, vf0, O[j], 0, 0, 0);  \
      bf16x8 vf1 = *(const bf16x8*)&Vs[vb][(j * 16 + l16) * 64 + sw1];          \
      O[j] = __builtin_amdgcn_mfma_f32_16x16x32_bf16(pf1, vf1, O[j], 0, 0, 0);  \
    }                                                                           \
    Ol = __builtin_amdgcn_mfma_f32_16x16x32_bf16(pf0, onesf, Ol, 0, 0, 0);      \
    Ol = __builtin_amdgcn_mfma_f32_16x16x32_bf16(pf1, onesf, Ol, 0, 0, 0);      \
    __builtin_amdgcn_s_setprio(0); }

  // pipeline prologue: stage K tile 1, compute S^T(0)
  STAGE_K(1, 1)                 // unconditional: rows stay in-bounds, buf unused if qt==0
  S_TILE(s_cur, 0)
  __syncthreads();              // drains stage K(1)

  for (int t = 0; t < qt; ++t) {
    EXP_P(s_cur, false)                    // VALU of tile t ...
    STAGE_V(t + 1, (t + 1) & 1)            // stages issued early: S_TILE+PV MFMAs
    if (t + 2 <= qt) STAGE_K(t + 2, t & 1) // cover the load latency pre-barrier
    S_TILE(s_next, (t + 1) & 1)            // ... overlaps MFMA of tile t+1
    PV_TILE(t & 1)
    __syncthreads();
#pragma unroll
    for (int m = 0; m < 4; ++m) s_cur[m] = s_next[m];
  }
  // diagonal (masked) tile
  EXP_P(s_cur, true)
  PV_TILE(qt & 1)

  // epilogue: l lives in col 0 of Ol (lanes l16==0); broadcast within quad
  const int rq = q0 + wave * 16 + quad * 4;
#pragma unroll
  for (int g = 0; g < 4; ++g) {
    const float lv = __shfl(Ol[g], quad * 16);
    const float inv = 1.0f / lv;
    const size_t rb = (size_t)(b * 2048 + rq + g) * 1024 + h * 64 + l16;
#pragma unroll
    for (int j = 0; j < 4; ++j)
      zb[rb + j * 16] = (__bf16)(O[j][g] * inv);
  }
}

// ---------------- launch ----------------
extern "C" void kernel_launch(void* const* d_in, const int* in_sizes, int n_in,
                              void* d_out, int out_size, void* d_ws, size_t ws_size,
                              hipStream_t stream) {
  (void)in_sizes; (void)n_in; (void)out_size; (void)ws_size;
  const float* x  = (const float*)d_in[0];
  const float* Wq = (const float*)d_in[1];
  const float* bq = (const float*)d_in[2];
  const float* Wk = (const float*)d_in[3];
  const float* bk = (const float*)d_in[4];
  const float* Wv = (const float*)d_in[5];
  const float* bv = (const float*)d_in[6];
  const float* Wo = (const float*)d_in[7];
  const float* bo = (const float*)d_in[8];

  char* ws = (char*)d_ws;
  __bf16* xb   = (__bf16*)(ws);                        // 8 MB
  __bf16* wqkv = (__bf16*)(ws + (8ull  << 20));        // 6 MB
  __bf16* wob  = (__bf16*)(ws + (14ull << 20));        // 2 MB
  float*  bqkv = (float*) (ws + (16ull << 20));        // 12 KB
  __bf16* qkv  = (__bf16*)(ws + (17ull << 20));        // 24 MB
  __bf16* vT   = (__bf16*)(ws + (41ull << 20));        // 8 MB  [bh][64][2048]
  __bf16* zb   = (__bf16*)(ws + (49ull << 20));        // 8 MB  (total 57 MB)

  cvt_kernel<<<4097, 256, 0, stream>>>(x, Wq, Wk, Wv, Wo, bq, bk, bv,
                                       xb, wqkv, wob, bqkv);
  gemm_k<128, 128, 1><<<dim3(24, 32), 256, 0, stream>>>(
      xb, wqkv, bqkv, nullptr, qkv, vT, Mx, 3072, 1024, 0);
  attn_mfma<<<1024, 256, 0, stream>>>(qkv, vT, zb);
  gemm_k<128, 64, 0><<<dim3(16, 32), 256, 0, stream>>>(
      zb, wob, bo, (float*)d_out, nullptr, nullptr, Mx, 1024, 1024, 1024);
}

// Round 3
// 179.085 us; speedup vs baseline: 1.0503x; 1.0230x over previous
//
#include <hip/hip_runtime.h>
#include <math.h>

#define Bx 2
#define Sx 2048
#define Dx 1024
#define Hx 16
#define HDx 64
#define Mx (Bx*Sx)   // 4096

typedef __bf16 bf16x8 __attribute__((ext_vector_type(8)));
typedef __bf16 bf16x4 __attribute__((ext_vector_type(4)));
typedef float  f32x4  __attribute__((ext_vector_type(4)));

// 0.125 (1/sqrt(64)) * log2(e): softmax in exp2 domain; folded into Q in GEMM1
#define SCL 0.18033688011112042f

__device__ __forceinline__ void gload_lds16(const __bf16* g, __bf16* l) {
  __builtin_amdgcn_global_load_lds(
      (const __attribute__((address_space(1))) unsigned int*)g,
      (__attribute__((address_space(3))) unsigned int*)l, 16, 0, 0);
}

// ---------------- fp32 -> bf16 conversion / weight concat ----------------
__device__ __forceinline__ void cvt8(const float* s, __bf16* d) {
  float4 a = *(const float4*)s;
  float4 b = *(const float4*)(s + 4);
  bf16x8 o;
  o[0] = (__bf16)a.x; o[1] = (__bf16)a.y; o[2] = (__bf16)a.z; o[3] = (__bf16)a.w;
  o[4] = (__bf16)b.x; o[5] = (__bf16)b.y; o[6] = (__bf16)b.z; o[7] = (__bf16)b.w;
  *(bf16x8*)d = o;
}

__global__ __launch_bounds__(256) void cvt_kernel(
    const float* __restrict__ x, const float* __restrict__ Wq,
    const float* __restrict__ Wk, const float* __restrict__ Wv,
    const float* __restrict__ Wo, const float* __restrict__ bq,
    const float* __restrict__ bk, const float* __restrict__ bv,
    __bf16* __restrict__ xb, __bf16* __restrict__ wqkv,
    __bf16* __restrict__ wob, float* __restrict__ bqkv)
{
  const int bid = blockIdx.x;
  const int t = threadIdx.x;
  const size_t MEG = 1024u * 1024u;
  if (bid < 2048) {
    size_t e = (size_t)bid * 2048 + t * 8;
    cvt8(x + e, xb + e);
  } else if (bid < 3584) {
    size_t e = (size_t)(bid - 2048) * 2048 + t * 8;
    const float* src = (e < MEG) ? (Wq + e) : (e < 2 * MEG) ? (Wk + (e - MEG)) : (Wv + (e - 2 * MEG));
    cvt8(src, wqkv + e);
  } else if (bid < 4096) {
    size_t e = (size_t)(bid - 3584) * 2048 + t * 8;
    cvt8(Wo + e, wob + e);
  } else {
    for (int i = t; i < 3072; i += 256)
      bqkv[i] = (i < 1024) ? bq[i] : (i < 2048) ? bk[i - 1024] : bv[i - 2048];
  }
}

// ---------------- bf16 MFMA GEMM, stage-ahead pipelined (unchanged) ----------
template<int TM, int TN, int MODE>
__global__ __launch_bounds__(256) void gemm_k(
    const __bf16* __restrict__ A, const __bf16* __restrict__ W,
    const float* __restrict__ bias, float* __restrict__ Cf,
    __bf16* __restrict__ Cb, __bf16* __restrict__ vT,
    int M, int N, int K, int ldc)
{
  __shared__ __align__(16) char smem[2 * (TM + TN) * 64 * 2];
  __bf16* AsB = (__bf16*)smem;

  constexpr int MS = TM / 32;
  constexpr int NS = TN / 32;
  const int tid = threadIdx.x;
  const int lane = tid & 63, wave = tid >> 6;
  const int l16 = lane & 15, quad = lane >> 4;
  const int wm = (wave >> 1) * (TM / 2);
  const int wn = (wave & 1) * (TN / 2);
  const int swz = l16 & 7;

  // 64-block supertile swizzle (8 m-tiles x 8 n-tiles)
  const int lid = blockIdx.y * gridDim.x + blockIdx.x;
  const int g8 = lid >> 6;
  const int r64 = lid & 63;
  const int gpm = (int)gridDim.y >> 3;
  const int gm = g8 % gpm;
  const int gn = g8 / gpm;
  const int m0 = (gm * 8 + (r64 & 7)) * TM;
  const int n0 = (gn * 8 + (r64 >> 3)) * TN;

  const f32x4 zero = {0.f, 0.f, 0.f, 0.f};
  f32x4 acc[MS][NS];
#pragma unroll
  for (int i = 0; i < MS; ++i)
#pragma unroll
    for (int j = 0; j < NS; ++j) acc[i][j] = zero;

  const int srow = tid >> 3;
  const int scs = (tid & 7) ^ (srow & 7);
  const __bf16* Ag = A + (size_t)(m0 + srow) * K + scs * 8;
  const __bf16* Wg = W + (size_t)(n0 + srow) * K + scs * 8;

#define G_STAGE(k0_, b_)                                                        \
  { __bf16* As_ = AsB + (b_) * (TM + TN) * 64;                                  \
    __bf16* Bs_ = As_ + TM * 64;                                                \
    _Pragma("unroll")                                                           \
    for (int i = 0; i < TM / 32; ++i)                                           \
      gload_lds16(Ag + (size_t)(i * 32) * K + (k0_), &As_[(i * 256 + tid) * 8]);\
    _Pragma("unroll")                                                           \
    for (int i = 0; i < TN / 32; ++i)                                           \
      gload_lds16(Wg + (size_t)(i * 32) * K + (k0_), &Bs_[(i * 256 + tid) * 8]); }

  const int NT = K >> 6;
  G_STAGE(0, 0)
  __syncthreads();

  for (int t = 0; t < NT; ++t) {
    if (t + 1 < NT) G_STAGE((t + 1) << 6, (t + 1) & 1)
    const __bf16* As_ = AsB + (t & 1) * (TM + TN) * 64;
    const __bf16* Bs_ = As_ + TM * 64;
#pragma unroll
    for (int hk = 0; hk < 2; ++hk) {
      const int ph = ((hk * 4 + quad) ^ swz) * 8;
      bf16x8 af[MS], bfr[NS];
#pragma unroll
      for (int i = 0; i < MS; ++i)
        af[i] = *(const bf16x8*)&As_[(wm + i * 16 + l16) * 64 + ph];
#pragma unroll
      for (int j = 0; j < NS; ++j)
        bfr[j] = *(const bf16x8*)&Bs_[(wn + j * 16 + l16) * 64 + ph];
#pragma unroll
      for (int i = 0; i < MS; ++i)
#pragma unroll
        for (int j = 0; j < NS; ++j)
          acc[i][j] = __builtin_amdgcn_mfma_f32_16x16x32_bf16(af[i], bfr[j], acc[i][j], 0, 0, 0);
    }
    __syncthreads();   // (a) everyone done with buf t; (b) stage(t+1) drained
  }

  // ---- epilogue: stage C tile in LDS (aliases staging bufs), 16B stores ----
  if (MODE == 0) {
    float* Cs = (float*)smem;          // [TM][TN+4]
    constexpr int cst = TN + 4;
#pragma unroll
    for (int j = 0; j < NS; ++j) {
      const int c = wn + j * 16 + l16;
      const float bv_ = bias[n0 + c];
#pragma unroll
      for (int i = 0; i < MS; ++i) {
        const int r0 = wm + i * 16 + quad * 4;
#pragma unroll
        for (int g = 0; g < 4; ++g)
          Cs[(r0 + g) * cst + c] = acc[i][j][g] + bv_;
      }
    }
    __syncthreads();
    constexpr int passes = TM * TN / (256 * 4);
#pragma unroll
    for (int p = 0; p < passes; ++p) {
      const int slot = p * 256 + tid;
      const int row = slot / (TN / 4);
      const int col4 = (slot % (TN / 4)) * 4;
      f32x4 v = *(const f32x4*)&Cs[row * cst + col4];
      *(f32x4*)&Cf[(size_t)(m0 + row) * ldc + n0 + col4] = v;
    }
  } else {
    __bf16* Cs = (__bf16*)smem;
    constexpr int cst = TN + 8;
    const bool vtile = (n0 >= 2048);
    if (!vtile) {
#pragma unroll
      for (int j = 0; j < NS; ++j) {
        const int c = wn + j * 16 + l16;
        const float bv_ = bias[n0 + c];
        const float sc = ((n0 + c) < 1024) ? SCL : 1.0f;
#pragma unroll
        for (int i = 0; i < MS; ++i) {
          const int r0 = wm + i * 16 + quad * 4;
#pragma unroll
          for (int g = 0; g < 4; ++g)
            Cs[(r0 + g) * cst + c] = (__bf16)((acc[i][j][g] + bv_) * sc);
        }
      }
      __syncthreads();
      constexpr int passes = TM * TN / (256 * 8);
#pragma unroll
      for (int p = 0; p < passes; ++p) {
        const int slot = p * 256 + tid;
        const int row = slot / (TN / 8);
        const int col8 = (slot % (TN / 8)) * 8;
        bf16x8 v = *(const bf16x8*)&Cs[row * cst + col8];
        *(bf16x8*)&Cb[(size_t)(m0 + row) * 3072 + n0 + col8] = v;
      }
    } else {
      constexpr int cstT = TM + 8;
#pragma unroll
      for (int j = 0; j < NS; ++j) {
        const int c = wn + j * 16 + l16;
        const float bv_ = bias[n0 + c];
#pragma unroll
        for (int i = 0; i < MS; ++i) {
          const int r0 = wm + i * 16 + quad * 4;
#pragma unroll
          for (int g = 0; g < 4; ++g)
            Cs[c * cstT + r0 + g] = (__bf16)(acc[i][j][g] + bv_);
        }
      }
      __syncthreads();
      const int bb = m0 >> 11, ml = m0 & 2047;
      constexpr int passes = TM * TN / (256 * 8);
#pragma unroll
      for (int p = 0; p < passes; ++p) {
        const int slot = p * 256 + tid;
        const int dd = slot / (TM / 8);
        const int ss8 = (slot % (TM / 8)) * 8;
        bf16x8 v = *(const bf16x8*)&Cs[dd * cstT + ss8];
        const int c2 = n0 - 2048 + dd;
        const int hh = c2 >> 6, ddd = c2 & 63;
        *(bf16x8*)&vT[((size_t)(bb * 16 + hh) * 64 + ddd) * 2048 + ml + ss8] = v;
      }
    }
  }
}

// ---------------- MFMA flash attention, S^T formulation ----------------
// r13: LDS-BW reduction. Accounting showed ~34us of the 44us attn is LDS
// service; K-frags were read 4x redundantly (every wave read all 64 key rows).
// Now: wave owns 16 KEYS in S^T (reads only its 2 K-frags/tile); all 64 q held
// in registers as 8 loop-invariant B-frags. EXP_P scatters the wave's
// 16key x 64q P slice into the full 64x64 P buffer (same XOR swizzle), so the
// PV stage is unchanged (wave owns 16 q there). P is now cross-wave-produced
// -> 2 barriers/tile (EXP -> bar -> PV -> bar). LDS reads/block-tile 72->48KB.
__global__ __launch_bounds__(256, 4) void attn_mfma(
    const __bf16* __restrict__ qkv, const __bf16* __restrict__ vT,
    __bf16* __restrict__ zb)
{
  __shared__ __bf16 Qs[64 * 64];      // Q; later the full 64x64 P buffer
  __shared__ __bf16 Ks[2][64 * 64];
  __shared__ __bf16 Vs[2][64 * 64];   // [d][k] (from vT)

  const int tid = threadIdx.x;
  const int lane = tid & 63, wave = tid >> 6;
  const int l16 = lane & 15, quad = lane >> 4;
  const int bx = blockIdx.x;
  const int bh = bx & 31;
  const int s8 = (bx >> 5) & 7;
  const int p4 = bx >> 8;
  const int qt = (p4 == 0) ? s8 : (p4 == 1) ? 15 - s8 : (p4 == 2) ? 16 + s8 : 31 - s8;
  const int h = bh & 15, b = bh >> 4;
  const int q0 = qt * 64;

  const __bf16* qg = qkv + (size_t)b * 2048 * 3072 + h * 64;
  const __bf16* kg = qg + 1024;
  const __bf16* vg = vT + (size_t)bh * 64 * 2048;

#define STAGE_K(kt_, kbuf)                                                      \
  { const int kn = (kt_) * 64;                                                  \
    _Pragma("unroll")                                                           \
    for (int i = 0; i < 2; ++i) {                                               \
      int slot = i * 256 + tid;                                                 \
      int row = slot >> 3, ph2 = slot & 7;                                      \
      int cs = ph2 ^ (row & 7);                                                 \
      gload_lds16(kg + (size_t)(kn + row) * 3072 + cs * 8, &Ks[kbuf][slot * 8]);\
    } }

#define STAGE_V(kt_, vbuf)                                                      \
  { const int kn = (kt_) * 64;                                                  \
    _Pragma("unroll")                                                           \
    for (int i = 0; i < 2; ++i) {                                               \
      int slot = i * 256 + tid;                                                 \
      int row = slot >> 3, ph2 = slot & 7;                                      \
      int cs = ph2 ^ (row & 7);                                                 \
      gload_lds16(vg + (size_t)row * 2048 + kn + cs * 8, &Vs[vbuf][slot * 8]);  \
    } }

  // prologue: Q + K/V tile 0
#pragma unroll
  for (int i = 0; i < 2; ++i) {
    int slot = i * 256 + tid;
    int row = slot >> 3, ph2 = slot & 7;
    int cs = ph2 ^ (row & 7);
    gload_lds16(qg + (size_t)(q0 + row) * 3072 + cs * 8, &Qs[slot * 8]);
  }
  STAGE_K(0, 0)
  STAGE_V(0, 0)
  __syncthreads();

  const int swz = l16 & 7;
  const int sw0 = ((quad) ^ swz) * 8;
  const int sw1 = ((quad + 4) ^ swz) * 8;

  // ALL 64 q rows as loop-invariant B-frags (n-tile x k-half), 32 VGPR
  bf16x8 qf0[4], qf1[4];
#pragma unroll
  for (int n = 0; n < 4; ++n) {
    qf0[n] = *(const bf16x8*)&Qs[(n * 16 + l16) * 64 + sw0];
    qf1[n] = *(const bf16x8*)&Qs[(n * 16 + l16) * 64 + sw1];
  }
  __bf16* Pf = Qs;                    // full 64x64 P buffer [q][key], swizzled
  __bf16* P = &Qs[wave * 16 * 64];    // PV view: this wave's 16 q rows

  // ones B-frag: B[n=0][k]=1 -> col 0 of Ol = row-sum of P (the l vector)
  bf16x8 onesf;
  {
    __bf16 ov = (l16 == 0) ? (__bf16)1.0f : (__bf16)0.0f;
#pragma unroll
    for (int i = 0; i < 8; ++i) onesf[i] = ov;
  }

  const f32x4 zero = {0.f, 0.f, 0.f, 0.f};
  f32x4 O[4], Ol = zero;
#pragma unroll
  for (int j = 0; j < 4; ++j) O[j] = zero;
  // S^T acc: wave owns keys [16*wave,16*wave+16); s[n] = those keys x q-tile n.
  // lane layout: key = 16*wave + quad*4 + g, q = n*16 + l16.
  f32x4 s_cur[4], s_next[4];

#define S_TILE(sdst, kb)                                                        \
  { __builtin_amdgcn_s_setprio(1);                                              \
    bf16x8 kf0 = *(const bf16x8*)&Ks[kb][(wave * 16 + l16) * 64 + sw0];         \
    bf16x8 kf1 = *(const bf16x8*)&Ks[kb][(wave * 16 + l16) * 64 + sw1];         \
    _Pragma("unroll")                                                           \
    for (int n = 0; n < 4; ++n) {                                               \
      sdst[n] = zero;                                                           \
      sdst[n] = __builtin_amdgcn_mfma_f32_16x16x32_bf16(kf0, qf0[n], sdst[n],0,0,0);\
      sdst[n] = __builtin_amdgcn_mfma_f32_16x16x32_bf16(kf1, qf1[n], sdst[n],0,0,0);\
    }                                                                           \
    __builtin_amdgcn_s_setprio(0); }

  // write P[q = n*16+l16][key = wave*16 + quad*4 + g]; 8-elem chunk
  // h = 2*wave + (quad>>1), swizzled h^(q&7) = h^(l16&7), half = quad&1
#define EXP_P(s, DIAG)                                                          \
  { _Pragma("unroll")                                                           \
    for (int n = 0; n < 4; ++n) {                                               \
      const int ql = n * 16 + l16;                                              \
      bf16x4 st;                                                                \
      _Pragma("unroll")                                                         \
      for (int g = 0; g < 4; ++g) {                                             \
        float p = __builtin_exp2f(s[n][g]);                                     \
        if (DIAG && (wave * 16 + quad * 4 + g) > ql) p = 0.f;                   \
        st[g] = (__bf16)p;                                                      \
      }                                                                         \
      *(bf16x4*)&Pf[ql * 64 + (((2 * wave + (quad >> 1)) ^ swz) * 8) + (quad & 1) * 4] = st; \
    } }

#define PV_TILE(vb)                                                             \
  { bf16x8 pf0 = *(const bf16x8*)&P[l16 * 64 + sw0];                            \
    bf16x8 pf1 = *(const bf16x8*)&P[l16 * 64 + sw1];                            \
    __builtin_amdgcn_s_setprio(1);                                              \
    _Pragma("unroll")                                                           \
    for (int j = 0; j < 4; ++j) {                                               \
      bf16x8 vf0 = *(const bf16x8*)&Vs[vb][(j * 16 + l16) * 64 + sw0];          \
      O[j] = __builtin_amdgcn_mfma_f32_16x16x32_bf16(pf0, vf0, O[j], 0, 0, 0);  \
      bf16x8 vf1 = *(const bf16x8*)&Vs[vb][(j * 16 + l16) * 64 + sw1];          \
      O[j] = __builtin_amdgcn_mfma_f32_16x16x32_bf16(pf1, vf1, O[j], 0, 0, 0);  \
    }                                                                           \
    Ol = __builtin_amdgcn_mfma_f32_16x16x32_bf16(pf0, onesf, Ol, 0, 0, 0);      \
    Ol = __builtin_amdgcn_mfma_f32_16x16x32_bf16(pf1, onesf, Ol, 0, 0, 0);      \
    __builtin_amdgcn_s_setprio(0); }

  // pipeline prologue: stage K tile 1, compute S^T(0)
  STAGE_K(1, 1)                 // unconditional: rows stay in-bounds, buf unused if qt==0
  S_TILE(s_cur, 0)
  __syncthreads();              // drains stage K(1); all qf reads complete

  for (int t = 0; t < qt; ++t) {
    STAGE_V(t + 1, (t + 1) & 1)            // stages first: max distance to drain
    if (t + 2 <= qt) STAGE_K(t + 2, t & 1)
    EXP_P(s_cur, false)                    // write P(t) into full buffer
    S_TILE(s_next, (t + 1) & 1)            // MFMA covers stage latency
    __syncthreads();                       // P(t) visible; stages drained
    PV_TILE(t & 1)
    __syncthreads();                       // PV done before next EXP_P overwrite
#pragma unroll
    for (int n = 0; n < 4; ++n) s_cur[n] = s_next[n];
  }
  // diagonal (masked) tile
  EXP_P(s_cur, true)
  __syncthreads();
  PV_TILE(qt & 1)

  // epilogue: l lives in col 0 of Ol (lanes l16==0); broadcast within quad
  const int rq = q0 + wave * 16 + quad * 4;
#pragma unroll
  for (int g = 0; g < 4; ++g) {
    const float lv = __shfl(Ol[g], quad * 16);
    const float inv = 1.0f / lv;
    const size_t rb = (size_t)(b * 2048 + rq + g) * 1024 + h * 64 + l16;
#pragma unroll
    for (int j = 0; j < 4; ++j)
      zb[rb + j * 16] = (__bf16)(O[j][g] * inv);
  }
}

// ---------------- launch ----------------
extern "C" void kernel_launch(void* const* d_in, const int* in_sizes, int n_in,
                              void* d_out, int out_size, void* d_ws, size_t ws_size,
                              hipStream_t stream) {
  (void)in_sizes; (void)n_in; (void)out_size; (void)ws_size;
  const float* x  = (const float*)d_in[0];
  const float* Wq = (const float*)d_in[1];
  const float* bq = (const float*)d_in[2];
  const float* Wk = (const float*)d_in[3];
  const float* bk = (const float*)d_in[4];
  const float* Wv = (const float*)d_in[5];
  const float* bv = (const float*)d_in[6];
  const float* Wo = (const float*)d_in[7];
  const float* bo = (const float*)d_in[8];

  char* ws = (char*)d_ws;
  __bf16* xb   = (__bf16*)(ws);                        // 8 MB
  __bf16* wqkv = (__bf16*)(ws + (8ull  << 20));        // 6 MB
  __bf16* wob  = (__bf16*)(ws + (14ull << 20));        // 2 MB
  float*  bqkv = (float*) (ws + (16ull << 20));        // 12 KB
  __bf16* qkv  = (__bf16*)(ws + (17ull << 20));        // 24 MB
  __bf16* vT   = (__bf16*)(ws + (41ull << 20));        // 8 MB  [bh][64][2048]
  __bf16* zb   = (__bf16*)(ws + (49ull << 20));        // 8 MB  (total 57 MB)

  cvt_kernel<<<4097, 256, 0, stream>>>(x, Wq, Wk, Wv, Wo, bq, bk, bv,
                                       xb, wqkv, wob, bqkv);
  gemm_k<128, 128, 1><<<dim3(24, 32), 256, 0, stream>>>(
      xb, wqkv, bqkv, nullptr, qkv, vT, Mx, 3072, 1024, 0);
  attn_mfma<<<1024, 256, 0, stream>>>(qkv, vT, zb);
  gemm_k<128, 64, 0><<<dim3(16, 32), 256, 0, stream>>>(
      zb, wob, bo, (float*)d_out, nullptr, nullptr, Mx, 1024, 1024, 1024);
}

// Round 5
// 175.690 us; speedup vs baseline: 1.0706x; 1.0193x over previous
//
#include <hip/hip_runtime.h>
#include <math.h>

#define Bx 2
#define Sx 2048
#define Dx 1024
#define Hx 16
#define HDx 64
#define Mx (Bx*Sx)   // 4096

typedef __bf16 bf16x8 __attribute__((ext_vector_type(8)));
typedef __bf16 bf16x4 __attribute__((ext_vector_type(4)));
typedef float  f32x4  __attribute__((ext_vector_type(4)));

// 0.125 (1/sqrt(64)) * log2(e): softmax in exp2 domain; folded into Q in GEMM1
#define SCL 0.18033688011112042f

__device__ __forceinline__ void gload_lds16(const __bf16* g, __bf16* l) {
  __builtin_amdgcn_global_load_lds(
      (const __attribute__((address_space(1))) unsigned int*)g,
      (__attribute__((address_space(3))) unsigned int*)l, 16, 0, 0);
}

// ---------------- fp32 -> bf16 conversion / weight concat ----------------
__device__ __forceinline__ void cvt8(const float* s, __bf16* d) {
  float4 a = *(const float4*)s;
  float4 b = *(const float4*)(s + 4);
  bf16x8 o;
  o[0] = (__bf16)a.x; o[1] = (__bf16)a.y; o[2] = (__bf16)a.z; o[3] = (__bf16)a.w;
  o[4] = (__bf16)b.x; o[5] = (__bf16)b.y; o[6] = (__bf16)b.z; o[7] = (__bf16)b.w;
  *(bf16x8*)d = o;
}

__global__ __launch_bounds__(256) void cvt_kernel(
    const float* __restrict__ x, const float* __restrict__ Wq,
    const float* __restrict__ Wk, const float* __restrict__ Wv,
    const float* __restrict__ Wo, const float* __restrict__ bq,
    const float* __restrict__ bk, const float* __restrict__ bv,
    __bf16* __restrict__ xb, __bf16* __restrict__ wqkv,
    __bf16* __restrict__ wob, float* __restrict__ bqkv)
{
  const int bid = blockIdx.x;
  const int t = threadIdx.x;
  const size_t MEG = 1024u * 1024u;
  if (bid < 2048) {
    size_t e = (size_t)bid * 2048 + t * 8;
    cvt8(x + e, xb + e);
  } else if (bid < 3584) {
    size_t e = (size_t)(bid - 2048) * 2048 + t * 8;
    const float* src = (e < MEG) ? (Wq + e) : (e < 2 * MEG) ? (Wk + (e - MEG)) : (Wv + (e - 2 * MEG));
    cvt8(src, wqkv + e);
  } else if (bid < 4096) {
    size_t e = (size_t)(bid - 3584) * 2048 + t * 8;
    cvt8(Wo + e, wob + e);
  } else {
    for (int i = t; i < 3072; i += 256)
      bqkv[i] = (i < 1024) ? bq[i] : (i < 2048) ? bk[i - 1024] : bv[i - 2048];
  }
}

// ---------------- bf16 MFMA GEMM, stage-ahead pipelined (unchanged) ----------
template<int TM, int TN, int MODE>
__global__ __launch_bounds__(256) void gemm_k(
    const __bf16* __restrict__ A, const __bf16* __restrict__ W,
    const float* __restrict__ bias, float* __restrict__ Cf,
    __bf16* __restrict__ Cb, __bf16* __restrict__ vT,
    int M, int N, int K, int ldc)
{
  __shared__ __align__(16) char smem[2 * (TM + TN) * 64 * 2];
  __bf16* AsB = (__bf16*)smem;

  constexpr int MS = TM / 32;
  constexpr int NS = TN / 32;
  const int tid = threadIdx.x;
  const int lane = tid & 63, wave = tid >> 6;
  const int l16 = lane & 15, quad = lane >> 4;
  const int wm = (wave >> 1) * (TM / 2);
  const int wn = (wave & 1) * (TN / 2);
  const int swz = l16 & 7;

  // 64-block supertile swizzle (8 m-tiles x 8 n-tiles)
  const int lid = blockIdx.y * gridDim.x + blockIdx.x;
  const int g8 = lid >> 6;
  const int r64 = lid & 63;
  const int gpm = (int)gridDim.y >> 3;
  const int gm = g8 % gpm;
  const int gn = g8 / gpm;
  const int m0 = (gm * 8 + (r64 & 7)) * TM;
  const int n0 = (gn * 8 + (r64 >> 3)) * TN;

  const f32x4 zero = {0.f, 0.f, 0.f, 0.f};
  f32x4 acc[MS][NS];
#pragma unroll
  for (int i = 0; i < MS; ++i)
#pragma unroll
    for (int j = 0; j < NS; ++j) acc[i][j] = zero;

  const int srow = tid >> 3;
  const int scs = (tid & 7) ^ (srow & 7);
  const __bf16* Ag = A + (size_t)(m0 + srow) * K + scs * 8;
  const __bf16* Wg = W + (size_t)(n0 + srow) * K + scs * 8;

#define G_STAGE(k0_, b_)                                                        \
  { __bf16* As_ = AsB + (b_) * (TM + TN) * 64;                                  \
    __bf16* Bs_ = As_ + TM * 64;                                                \
    _Pragma("unroll")                                                           \
    for (int i = 0; i < TM / 32; ++i)                                           \
      gload_lds16(Ag + (size_t)(i * 32) * K + (k0_), &As_[(i * 256 + tid) * 8]);\
    _Pragma("unroll")                                                           \
    for (int i = 0; i < TN / 32; ++i)                                           \
      gload_lds16(Wg + (size_t)(i * 32) * K + (k0_), &Bs_[(i * 256 + tid) * 8]); }

  const int NT = K >> 6;
  G_STAGE(0, 0)
  __syncthreads();

  for (int t = 0; t < NT; ++t) {
    if (t + 1 < NT) G_STAGE((t + 1) << 6, (t + 1) & 1)
    const __bf16* As_ = AsB + (t & 1) * (TM + TN) * 64;
    const __bf16* Bs_ = As_ + TM * 64;
#pragma unroll
    for (int hk = 0; hk < 2; ++hk) {
      const int ph = ((hk * 4 + quad) ^ swz) * 8;
      bf16x8 af[MS], bfr[NS];
#pragma unroll
      for (int i = 0; i < MS; ++i)
        af[i] = *(const bf16x8*)&As_[(wm + i * 16 + l16) * 64 + ph];
#pragma unroll
      for (int j = 0; j < NS; ++j)
        bfr[j] = *(const bf16x8*)&Bs_[(wn + j * 16 + l16) * 64 + ph];
#pragma unroll
      for (int i = 0; i < MS; ++i)
#pragma unroll
        for (int j = 0; j < NS; ++j)
          acc[i][j] = __builtin_amdgcn_mfma_f32_16x16x32_bf16(af[i], bfr[j], acc[i][j], 0, 0, 0);
    }
    __syncthreads();   // (a) everyone done with buf t; (b) stage(t+1) drained
  }

  // ---- epilogue: stage C tile in LDS (aliases staging bufs), 16B stores ----
  if (MODE == 0) {
    float* Cs = (float*)smem;          // [TM][TN+4]
    constexpr int cst = TN + 4;
#pragma unroll
    for (int j = 0; j < NS; ++j) {
      const int c = wn + j * 16 + l16;
      const float bv_ = bias[n0 + c];
#pragma unroll
      for (int i = 0; i < MS; ++i) {
        const int r0 = wm + i * 16 + quad * 4;
#pragma unroll
        for (int g = 0; g < 4; ++g)
          Cs[(r0 + g) * cst + c] = acc[i][j][g] + bv_;
      }
    }
    __syncthreads();
    constexpr int passes = TM * TN / (256 * 4);
#pragma unroll
    for (int p = 0; p < passes; ++p) {
      const int slot = p * 256 + tid;
      const int row = slot / (TN / 4);
      const int col4 = (slot % (TN / 4)) * 4;
      f32x4 v = *(const f32x4*)&Cs[row * cst + col4];
      *(f32x4*)&Cf[(size_t)(m0 + row) * ldc + n0 + col4] = v;
    }
  } else {
    __bf16* Cs = (__bf16*)smem;
    constexpr int cst = TN + 8;
    const bool vtile = (n0 >= 2048);
    if (!vtile) {
#pragma unroll
      for (int j = 0; j < NS; ++j) {
        const int c = wn + j * 16 + l16;
        const float bv_ = bias[n0 + c];
        const float sc = ((n0 + c) < 1024) ? SCL : 1.0f;
#pragma unroll
        for (int i = 0; i < MS; ++i) {
          const int r0 = wm + i * 16 + quad * 4;
#pragma unroll
          for (int g = 0; g < 4; ++g)
            Cs[(r0 + g) * cst + c] = (__bf16)((acc[i][j][g] + bv_) * sc);
        }
      }
      __syncthreads();
      constexpr int passes = TM * TN / (256 * 8);
#pragma unroll
      for (int p = 0; p < passes; ++p) {
        const int slot = p * 256 + tid;
        const int row = slot / (TN / 8);
        const int col8 = (slot % (TN / 8)) * 8;
        bf16x8 v = *(const bf16x8*)&Cs[row * cst + col8];
        *(bf16x8*)&Cb[(size_t)(m0 + row) * 3072 + n0 + col8] = v;
      }
    } else {
      constexpr int cstT = TM + 8;
#pragma unroll
      for (int j = 0; j < NS; ++j) {
        const int c = wn + j * 16 + l16;
        const float bv_ = bias[n0 + c];
#pragma unroll
        for (int i = 0; i < MS; ++i) {
          const int r0 = wm + i * 16 + quad * 4;
#pragma unroll
          for (int g = 0; g < 4; ++g)
            Cs[c * cstT + r0 + g] = (__bf16)(acc[i][j][g] + bv_);
        }
      }
      __syncthreads();
      const int bb = m0 >> 11, ml = m0 & 2047;
      constexpr int passes = TM * TN / (256 * 8);
#pragma unroll
      for (int p = 0; p < passes; ++p) {
        const int slot = p * 256 + tid;
        const int dd = slot / (TM / 8);
        const int ss8 = (slot % (TM / 8)) * 8;
        bf16x8 v = *(const bf16x8*)&Cs[dd * cstT + ss8];
        const int c2 = n0 - 2048 + dd;
        const int hh = c2 >> 6, ddd = c2 & 63;
        *(bf16x8*)&vT[((size_t)(bb * 16 + hh) * 64 + ddd) * 2048 + ml + ss8] = v;
      }
    }
  }
}

// ---------------- MFMA flash attention, register-P formulation ----------------
// r15: kill the P LDS round-trip. S^T = K.Q^T with wave-owning-16-keys (r13,
// verified) puts exp(S) exactly in the PV B-frag layout (B[k][n]: n=l16,
// k=quad*8+j): PV consumes P from REGISTERS. Each wave accumulates a partial
// O^T[d][q] over its 16-key slice (K=32 MFMA, upper 4 k-slots zeroed on BOTH
// operands), V read = one b64 per d-tile. l = 16 VALU adds (no Ol MFMAs).
// One barrier/tile. LDS traffic/tile: ~96KB -> ~32KB. Partial O's merged once
// per block by a 4-wave LDS tree (redA/redB alias K/V bufs after final sync).
__global__ __launch_bounds__(256, 3) void attn_mfma(
    const __bf16* __restrict__ qkv, const __bf16* __restrict__ vT,
    __bf16* __restrict__ zb)
{
  __shared__ __bf16 Qs[64 * 64];      // Q frags; later l-reduction scratch
  __shared__ __bf16 Ks[2][64 * 64];   // later redA (16KB)
  __shared__ __bf16 Vs[2][64 * 64];   // [d][k]; later redB (16KB)

  const int tid = threadIdx.x;
  const int lane = tid & 63, wave = tid >> 6;
  const int l16 = lane & 15, quad = lane >> 4;
  const int bx = blockIdx.x;
  const int qt = 31 - (bx >> 5);      // heavy q-tiles dispatched first
  const int bh = bx & 31;
  const int h = bh & 15, b = bh >> 4;
  const int q0 = qt * 64;

  const __bf16* qg = qkv + (size_t)b * 2048 * 3072 + h * 64;
  const __bf16* kg = qg + 1024;
  const __bf16* vg = vT + (size_t)bh * 64 * 2048;

#define STAGE_K(kt_, kbuf)                                                      \
  { const int kn = (kt_) * 64;                                                  \
    _Pragma("unroll")                                                           \
    for (int i = 0; i < 2; ++i) {                                               \
      int slot = i * 256 + tid;                                                 \
      int row = slot >> 3, ph2 = slot & 7;                                      \
      int cs = ph2 ^ (row & 7);                                                 \
      gload_lds16(kg + (size_t)(kn + row) * 3072 + cs * 8, &Ks[kbuf][slot * 8]);\
    } }

#define STAGE_V(kt_, vbuf)                                                      \
  { const int kn = (kt_) * 64;                                                  \
    _Pragma("unroll")                                                           \
    for (int i = 0; i < 2; ++i) {                                               \
      int slot = i * 256 + tid;                                                 \
      int row = slot >> 3, ph2 = slot & 7;                                      \
      int cs = ph2 ^ (row & 7);                                                 \
      gload_lds16(vg + (size_t)row * 2048 + kn + cs * 8, &Vs[vbuf][slot * 8]);  \
    } }

  // prologue: Q + K/V tile 0
#pragma unroll
  for (int i = 0; i < 2; ++i) {
    int slot = i * 256 + tid;
    int row = slot >> 3, ph2 = slot & 7;
    int cs = ph2 ^ (row & 7);
    gload_lds16(qg + (size_t)(q0 + row) * 3072 + cs * 8, &Qs[slot * 8]);
  }
  STAGE_K(0, 0)
  STAGE_V(0, 0)
  __syncthreads();

  const int swz = l16 & 7;
  const int sw0 = ((quad) ^ swz) * 8;
  const int sw1 = ((quad + 4) ^ swz) * 8;
  // V A-frag column (loop-invariant): wave's 16 keys, this quad's 4,
  // through the 16B-chunk XOR swizzle (row&7 == l16&7 == swz for rows jt*16+l16)
  const int vcol = (((2 * wave + (quad >> 1)) ^ swz) * 8) + (quad & 1) * 4;
  const __bf16 ZB = (__bf16)0.0f;

  // ALL 64 q rows as loop-invariant B-frags for S^T (r13-verified layout)
  bf16x8 qf0[4], qf1[4];
#pragma unroll
  for (int n = 0; n < 4; ++n) {
    qf0[n] = *(const bf16x8*)&Qs[(n * 16 + l16) * 64 + sw0];
    qf1[n] = *(const bf16x8*)&Qs[(n * 16 + l16) * 64 + sw1];
  }

  const f32x4 zero = {0.f, 0.f, 0.f, 0.f};
  // partial O^T over this wave's 16 keys: acc[jt][n], lane = [d=jt*16+quad*4+g][q=n*16+l16]
  f32x4 acc[4][4];
#pragma unroll
  for (int jt = 0; jt < 4; ++jt)
#pragma unroll
    for (int n = 0; n < 4; ++n) acc[jt][n] = zero;
  float lacc[4] = {0.f, 0.f, 0.f, 0.f};
  f32x4 s[4];          // S^T: lane = [key=wave*16+quad*4+g][q=n*16+l16]
  bf16x8 pb[4];        // exp(S) as PV B-frags (upper 4 k-slots zero)

#define S_TILE(kb)                                                              \
  { __builtin_amdgcn_s_setprio(1);                                              \
    bf16x8 kf0 = *(const bf16x8*)&Ks[kb][(wave * 16 + l16) * 64 + sw0];         \
    bf16x8 kf1 = *(const bf16x8*)&Ks[kb][(wave * 16 + l16) * 64 + sw1];         \
    _Pragma("unroll")                                                           \
    for (int n = 0; n < 4; ++n) {                                               \
      s[n] = zero;                                                              \
      s[n] = __builtin_amdgcn_mfma_f32_16x16x32_bf16(kf0, qf0[n], s[n], 0, 0, 0);\
      s[n] = __builtin_amdgcn_mfma_f32_16x16x32_bf16(kf1, qf1[n], s[n], 0, 0, 0);\
    }                                                                           \
    __builtin_amdgcn_s_setprio(0); }

  const int kqb = wave * 16 + quad * 4;   // wave's key base (tile-local)

#define EXP_PB(DIAG)                                                            \
  { _Pragma("unroll")                                                           \
    for (int n = 0; n < 4; ++n) {                                               \
      const int ql = n * 16 + l16;                                              \
      float e0 = __builtin_exp2f(s[n][0]);                                      \
      float e1 = __builtin_exp2f(s[n][1]);                                      \
      float e2 = __builtin_exp2f(s[n][2]);                                      \
      float e3 = __builtin_exp2f(s[n][3]);                                      \
      if (DIAG) {                                                               \
        if (kqb + 0 > ql) e0 = 0.f;                                             \
        if (kqb + 1 > ql) e1 = 0.f;                                             \
        if (kqb + 2 > ql) e2 = 0.f;                                             \
        if (kqb + 3 > ql) e3 = 0.f;                                             \
      }                                                                         \
      pb[n] = (bf16x8){(__bf16)e0, (__bf16)e1, (__bf16)e2, (__bf16)e3,          \
                       ZB, ZB, ZB, ZB};                                         \
      lacc[n] += (e0 + e1) + (e2 + e3);                                         \
    } }

#define PV_TILE(vb)                                                             \
  { __builtin_amdgcn_s_setprio(1);                                              \
    _Pragma("unroll")                                                           \
    for (int jt = 0; jt < 4; ++jt) {                                            \
      bf16x4 vv = *(const bf16x4*)&Vs[vb][(jt * 16 + l16) * 64 + vcol];         \
      bf16x8 av = (bf16x8){vv[0], vv[1], vv[2], vv[3], ZB, ZB, ZB, ZB};         \
      _Pragma("unroll")                                                         \
      for (int n = 0; n < 4; ++n)                                               \
        acc[jt][n] = __builtin_amdgcn_mfma_f32_16x16x32_bf16(av, pb[n], acc[jt][n], 0, 0, 0); \
    }                                                                           \
    __builtin_amdgcn_s_setprio(0); }

  // pipeline prologue
  STAGE_K(1, 1)                 // in-bounds always; unused if qt==0
  S_TILE(0)
  __syncthreads();              // drains K(1); Qs reads complete

  for (int t = 0; t < qt; ++t) {
    EXP_PB(false)                           // s(t) -> pb (registers)
    STAGE_V(t + 1, (t + 1) & 1)             // stages early; MFMAs cover latency
    if (t + 2 <= qt) STAGE_K(t + 2, t & 1)
    S_TILE((t + 1) & 1)                     // overwrites s with tile t+1
    PV_TILE(t & 1)                          // consumes pb(t)
    __syncthreads();
  }
  // diagonal (masked) tile
  EXP_PB(true)
  PV_TILE(qt & 1)
  __syncthreads();              // all LDS reads done before reduction reuse

  // ---- cross-wave reduction of partial O (and l) ----
  float* redA = (float*)&Ks[0][0];   // 16 KB
  float* redB = (float*)&Vs[0][0];   // 16 KB
  float* lred = (float*)Qs;          // 1 KB used
#pragma unroll
  for (int n = 0; n < 4; ++n) {
    float v = lacc[n];
    v += __shfl_xor(v, 16);
    v += __shfl_xor(v, 32);
    lacc[n] = v;
  }
  if (quad == 0) {
#pragma unroll
    for (int n = 0; n < 4; ++n) lred[wave * 64 + n * 16 + l16] = lacc[n];
  }

#define WR_ACC(dst)                                                             \
  { _Pragma("unroll")                                                           \
    for (int jt = 0; jt < 4; ++jt)                                              \
      _Pragma("unroll")                                                         \
      for (int n = 0; n < 4; ++n)                                               \
        *(f32x4*)&dst[(jt * 4 + n) * 256 + lane * 4] = acc[jt][n]; }
#define ADD_ACC(srcp)                                                           \
  { _Pragma("unroll")                                                           \
    for (int jt = 0; jt < 4; ++jt)                                              \
      _Pragma("unroll")                                                         \
      for (int n = 0; n < 4; ++n) {                                             \
        f32x4 tmp = *(const f32x4*)&srcp[(jt * 4 + n) * 256 + lane * 4];        \
        acc[jt][n] += tmp;                                                      \
      } }

  if (wave == 1) WR_ACC(redA)
  if (wave == 3) WR_ACC(redB)
  __syncthreads();
  if (wave == 0) ADD_ACC(redA)
  if (wave == 2) ADD_ACC(redB)
  __syncthreads();
  if (wave == 2) WR_ACC(redA)
  __syncthreads();
  if (wave == 0) {
    ADD_ACC(redA)
    float inv[4];
#pragma unroll
    for (int n = 0; n < 4; ++n) {
      const float lsum = lred[n * 16 + l16] + lred[64 + n * 16 + l16]
                       + lred[128 + n * 16 + l16] + lred[192 + n * 16 + l16];
      inv[n] = 1.0f / lsum;
    }
#pragma unroll
    for (int jt = 0; jt < 4; ++jt)
#pragma unroll
      for (int n = 0; n < 4; ++n) {
        bf16x4 ov = (bf16x4){(__bf16)(acc[jt][n][0] * inv[n]),
                             (__bf16)(acc[jt][n][1] * inv[n]),
                             (__bf16)(acc[jt][n][2] * inv[n]),
                             (__bf16)(acc[jt][n][3] * inv[n])};
        *(bf16x4*)&zb[(size_t)(b * 2048 + q0 + n * 16 + l16) * 1024
                      + h * 64 + jt * 16 + quad * 4] = ov;
      }
  }
}

// ---------------- launch ----------------
extern "C" void kernel_launch(void* const* d_in, const int* in_sizes, int n_in,
                              void* d_out, int out_size, void* d_ws, size_t ws_size,
                              hipStream_t stream) {
  (void)in_sizes; (void)n_in; (void)out_size; (void)ws_size;
  const float* x  = (const float*)d_in[0];
  const float* Wq = (const float*)d_in[1];
  const float* bq = (const float*)d_in[2];
  const float* Wk = (const float*)d_in[3];
  const float* bk = (const float*)d_in[4];
  const float* Wv = (const float*)d_in[5];
  const float* bv = (const float*)d_in[6];
  const float* Wo = (const float*)d_in[7];
  const float* bo = (const float*)d_in[8];

  char* ws = (char*)d_ws;
  __bf16* xb   = (__bf16*)(ws);                        // 8 MB
  __bf16* wqkv = (__bf16*)(ws + (8ull  << 20));        // 6 MB
  __bf16* wob  = (__bf16*)(ws + (14ull << 20));        // 2 MB
  float*  bqkv = (float*) (ws + (16ull << 20));        // 12 KB
  __bf16* qkv  = (__bf16*)(ws + (17ull << 20));        // 24 MB
  __bf16* vT   = (__bf16*)(ws + (41ull << 20));        // 8 MB  [bh][64][2048]
  __bf16* zb   = (__bf16*)(ws + (49ull << 20));        // 8 MB  (total 57 MB)

  cvt_kernel<<<4097, 256, 0, stream>>>(x, Wq, Wk, Wv, Wo, bq, bk, bv,
                                       xb, wqkv, wob, bqkv);
  gemm_k<128, 128, 1><<<dim3(24, 32), 256, 0, stream>>>(
      xb, wqkv, bqkv, nullptr, qkv, vT, Mx, 3072, 1024, 0);
  attn_mfma<<<1024, 256, 0, stream>>>(qkv, vT, zb);
  gemm_k<128, 64, 0><<<dim3(16, 32), 256, 0, stream>>>(
      zb, wob, bo, (float*)d_out, nullptr, nullptr, Mx, 1024, 1024, 1024);
}